// Round 5
// baseline (40.657 us; speedup 1.0000x reference)
//
#include <hip/hip_runtime.h>
#include <hip/hip_bf16.h>

// CSPN step: out[b,y,x] = sum_{i,j} gw[b, i*3+j, y+1, x+1] * src[y+1-i, x+1-j]
// src = h0 for center tap (i=j=1), hn otherwise; zero outside [0,H)x[0,W).
// R0 per-thread body (1 px/thread, scalar loads) with a 64x4 2D block tiling
// so hn's 3-row vertical reuse is intra-block (same CU / same XCD L2).

constexpr int B = 8;
constexpr int H = 352;
constexpr int W = 1216;
constexpr int HP = H + 2;   // 354
constexpr int WP = W + 2;   // 1218
constexpr size_t PLANE = (size_t)HP * WP;

constexpr int TX = 64;      // tile width  (one wave = one x-line)
constexpr int TY = 4;       // tile height
constexpr int XT = W / TX;  // 19 x-tiles
constexpr int YT = H / TY;  // 88 y-tiles
constexpr int NBLK = XT * YT * B;   // 13376 blocks

__global__ __launch_bounds__(256) void cspn_r4_kernel(
    const float* __restrict__ gw,   // [B, 9, HP, WP]
    const float* __restrict__ hn,   // [B, 1, H, W]
    const float* __restrict__ h0,   // [B, 1, H, W]
    float* __restrict__ out)        // [B, 1, H, W]
{
    int bid = blockIdx.x;
    int xt = bid % XT;
    int t2 = bid / XT;
    int yt = t2 % YT;
    int b  = t2 / YT;

    int tx = threadIdx.x & 63;
    int ty = threadIdx.x >> 6;
    int x = xt * TX + tx;
    int y = yt * TY + ty;

    const float* gwb = gw + (size_t)b * 9 * PLANE + (size_t)(y + 1) * WP + (x + 1);
    const float* hnb = hn + (size_t)b * H * W;
    const float* h0b = h0 + (size_t)b * H * W;

    float acc = 0.0f;
#pragma unroll
    for (int i = 0; i < 3; ++i) {
        int yy = y + 1 - i;
        bool yin = (yy >= 0) & (yy < H);
#pragma unroll
        for (int j = 0; j < 3; ++j) {
            const int t = i * 3 + j;
            int xx = x + 1 - j;
            bool in = yin & (xx >= 0) & (xx < W);
            float s = 0.0f;
            if (in) {
                const float* src = (t == 4) ? h0b : hnb;
                s = src[(size_t)yy * W + xx];
            }
            acc = fmaf(gwb[(size_t)t * PLANE], s, acc);
        }
    }
    out[(size_t)b * H * W + (size_t)y * W + x] = acc;
}

extern "C" void kernel_launch(void* const* d_in, const int* in_sizes, int n_in,
                              void* d_out, int out_size, void* d_ws, size_t ws_size,
                              hipStream_t stream) {
    const float* gw = (const float*)d_in[0];
    const float* hn = (const float*)d_in[1];
    const float* h0 = (const float*)d_in[2];
    float* out = (float*)d_out;

    cspn_r4_kernel<<<NBLK, 256, 0, stream>>>(gw, hn, h0, out);
}

// Round 6
// 34.728 us; speedup vs baseline: 1.1707x; 1.1707x over previous
//
#include <hip/hip_runtime.h>
#include <hip/hip_bf16.h>

// CSPN step: out[b,y,x] = sum_{i,j} gw[b, i*3+j, y+1, x+1] * src[y+1-i, x+1-j]
// src = h0 for center tap (i=j=1), hn otherwise; zero outside [0,H)x[0,W).
// R5: linear 1D mapping (proven best), 4 px/thread, ONE dwordx4 per gw tap
// (align-4 vector load — gfx950 global loads need only dword alignment),
// branch-free edge masking (no dual-path divergence).

constexpr int B = 8;
constexpr int H = 352;
constexpr int W = 1216;
constexpr int HP = H + 2;            // 354
constexpr int WP = W + 2;            // 1218
constexpr int CPR = W / 4;           // 304 chunks per row, exact
constexpr size_t PLANE = (size_t)HP * WP;

typedef float f4  __attribute__((ext_vector_type(4)));               // 16B aligned
typedef float f4u __attribute__((ext_vector_type(4), aligned(4)));   // dword aligned

__global__ __launch_bounds__(256) void cspn_r5_kernel(
    const float* __restrict__ gw,   // [B, 9, HP, WP]
    const float* __restrict__ hn,   // [B, 1, H, W]
    const float* __restrict__ h0,   // [B, 1, H, W]
    float* __restrict__ out)        // [B, 1, H, W]
{
    int tid = blockIdx.x * 256 + threadIdx.x;
    int cx = tid % CPR;
    int t2 = tid / CPR;
    int y  = t2 % H;
    int b  = t2 / H;
    int x0 = cx * 4;

    const float* hnb = hn + (size_t)b * H * W;
    const float* h0p = h0 + (size_t)b * H * W + (size_t)y * W + x0;
    const float* gwp = gw + (size_t)b * 9 * PLANE + (size_t)(y + 1) * WP + (x0 + 1);
    float* outp = out + (size_t)b * H * W + (size_t)y * W + x0;

    // hn rows i=0..2 (row yy = y+1-i), cols x0-1 .. x0+4, masked OOB.
    float r[3][6];
    int aL = (cx > 0)       ? x0 - 1 : 0;      // clamped edge addresses
    int aR = (cx < CPR - 1) ? x0 + 4 : W - 1;
#pragma unroll
    for (int i = 0; i < 3; ++i) {
        bool ok = (i == 1) | ((i == 0) ? (y < H - 1) : (y > 0));
        int ay = (i == 0) ? ((y < H - 1) ? y + 1 : y)
               : (i == 2) ? ((y > 0) ? y - 1 : y) : y;
        const float* rp = hnb + (size_t)ay * W;
        float sL = rp[aL];
        f4 v = *reinterpret_cast<const f4*>(rp + x0);   // 16B aligned
        float sR = rp[aR];
        float m = ok ? 1.f : 0.f;
        r[i][0] = (ok & (cx > 0))       ? sL : 0.f;
        r[i][1] = v[0] * m; r[i][2] = v[1] * m;
        r[i][3] = v[2] * m; r[i][4] = v[3] * m;
        r[i][5] = (ok & (cx < CPR - 1)) ? sR : 0.f;
    }

    // h0 center row, always in-bounds, 16B aligned
    f4 c = *reinterpret_cast<const f4*>(h0p);

    float acc[4] = {0.f, 0.f, 0.f, 0.f};
#pragma unroll
    for (int i = 0; i < 3; ++i) {
#pragma unroll
        for (int j = 0; j < 3; ++j) {
            const int t = i * 3 + j;
            // cols x0+1 .. x0+4 of tap plane t — always in-bounds (gw padded),
            // one dwordx4 request: 1KB contiguous per wave per plane.
            f4u g = *reinterpret_cast<const f4u*>(gwp + (size_t)t * PLANE);
#pragma unroll
            for (int p = 0; p < 4; ++p) {
                float s = (t == 4) ? c[p] : r[i][p + 2 - j];
                acc[p] = fmaf(g[p], s, acc[p]);
            }
        }
    }

    f4 o; o[0] = acc[0]; o[1] = acc[1]; o[2] = acc[2]; o[3] = acc[3];
    *reinterpret_cast<f4*>(outp) = o;   // 16B aligned
}

extern "C" void kernel_launch(void* const* d_in, const int* in_sizes, int n_in,
                              void* d_out, int out_size, void* d_ws, size_t ws_size,
                              hipStream_t stream) {
    const float* gw = (const float*)d_in[0];
    const float* hn = (const float*)d_in[1];
    const float* h0 = (const float*)d_in[2];
    float* out = (float*)d_out;

    constexpr int total = B * H * CPR;       // 856064 threads
    constexpr int block = 256;
    constexpr int grid = total / block;      // 3344 exact
    cspn_r5_kernel<<<grid, block, 0, stream>>>(gw, hn, h0, out);
}

// Round 7
// 33.981 us; speedup vs baseline: 1.1965x; 1.0220x over previous
//
#include <hip/hip_runtime.h>
#include <hip/hip_bf16.h>

// CSPN step: out[b,y,x] = sum_{i,j} gw[b, i*3+j, y+1, x+1] * src[y+1-i, x+1-j]
// src = h0 for center tap (i=j=1), hn otherwise; zero outside [0,H)x[0,W).
// R6 = R5 (linear 1D mapping, 4 px/thread, one dwordx4 per gw tap) with ALL
// 14 loads explicitly issued before any FMA, maximizing per-wave MLP.

constexpr int B = 8;
constexpr int H = 352;
constexpr int W = 1216;
constexpr int HP = H + 2;            // 354
constexpr int WP = W + 2;            // 1218
constexpr int CPR = W / 4;           // 304 chunks per row, exact
constexpr size_t PLANE = (size_t)HP * WP;

typedef float f4  __attribute__((ext_vector_type(4)));               // 16B aligned
typedef float f4u __attribute__((ext_vector_type(4), aligned(4)));   // dword aligned

__global__ __launch_bounds__(256) void cspn_r6_kernel(
    const float* __restrict__ gw,   // [B, 9, HP, WP]
    const float* __restrict__ hn,   // [B, 1, H, W]
    const float* __restrict__ h0,   // [B, 1, H, W]
    float* __restrict__ out)        // [B, 1, H, W]
{
    int tid = blockIdx.x * 256 + threadIdx.x;
    int cx = tid % CPR;
    int t2 = tid / CPR;
    int y  = t2 % H;
    int b  = t2 / H;
    int x0 = cx * 4;

    const float* hnb = hn + (size_t)b * H * W;
    const float* h0p = h0 + (size_t)b * H * W + (size_t)y * W + x0;
    const float* gwp = gw + (size_t)b * 9 * PLANE + (size_t)(y + 1) * WP + (x0 + 1);
    float* outp = out + (size_t)b * H * W + (size_t)y * W + x0;

    // ---- issue ALL loads first (14 independent memory ops) ----
    // gw: 9 taps, one dwordx4 each
    f4u g[9];
#pragma unroll
    for (int t = 0; t < 9; ++t)
        g[t] = *reinterpret_cast<const f4u*>(gwp + (size_t)t * PLANE);

    // hn rows i=0..2 (row yy = y+1-i), cols x0-1 .. x0+4: f4 + 2 clamped scalars
    int aL = (cx > 0)       ? x0 - 1 : 0;
    int aR = (cx < CPR - 1) ? x0 + 4 : W - 1;
    int ay0 = (y < H - 1) ? y + 1 : y;     // clamped row for i=0
    int ay2 = (y > 0)     ? y - 1 : y;     // clamped row for i=2
    const float* rp0 = hnb + (size_t)ay0 * W;
    const float* rp1 = hnb + (size_t)y * W;
    const float* rp2 = hnb + (size_t)ay2 * W;

    f4 v0 = *reinterpret_cast<const f4*>(rp0 + x0);
    float sL0 = rp0[aL], sR0 = rp0[aR];
    f4 v1 = *reinterpret_cast<const f4*>(rp1 + x0);
    float sL1 = rp1[aL], sR1 = rp1[aR];
    f4 v2 = *reinterpret_cast<const f4*>(rp2 + x0);
    float sL2 = rp2[aL], sR2 = rp2[aR];

    // h0 center row, always in-bounds
    f4 c = *reinterpret_cast<const f4*>(h0p);

    // ---- masks / register shuffle (no memory) ----
    bool okL = (cx > 0), okR = (cx < CPR - 1);
    bool ok0 = (y < H - 1), ok2 = (y > 0);
    float m0 = ok0 ? 1.f : 0.f;
    float m2 = ok2 ? 1.f : 0.f;

    float r[3][6];
    r[0][0] = (ok0 & okL) ? sL0 : 0.f;
    r[0][1] = v0[0] * m0; r[0][2] = v0[1] * m0;
    r[0][3] = v0[2] * m0; r[0][4] = v0[3] * m0;
    r[0][5] = (ok0 & okR) ? sR0 : 0.f;

    r[1][0] = okL ? sL1 : 0.f;
    r[1][1] = v1[0]; r[1][2] = v1[1];
    r[1][3] = v1[2]; r[1][4] = v1[3];
    r[1][5] = okR ? sR1 : 0.f;

    r[2][0] = (ok2 & okL) ? sL2 : 0.f;
    r[2][1] = v2[0] * m2; r[2][2] = v2[1] * m2;
    r[2][3] = v2[2] * m2; r[2][4] = v2[3] * m2;
    r[2][5] = (ok2 & okR) ? sR2 : 0.f;

    // ---- FMAs ----
    float acc[4] = {0.f, 0.f, 0.f, 0.f};
#pragma unroll
    for (int i = 0; i < 3; ++i) {
#pragma unroll
        for (int j = 0; j < 3; ++j) {
            const int t = i * 3 + j;
#pragma unroll
            for (int p = 0; p < 4; ++p) {
                float s = (t == 4) ? c[p] : r[i][p + 2 - j];
                acc[p] = fmaf(g[t][p], s, acc[p]);
            }
        }
    }

    f4 o; o[0] = acc[0]; o[1] = acc[1]; o[2] = acc[2]; o[3] = acc[3];
    *reinterpret_cast<f4*>(outp) = o;   // 16B aligned
}

extern "C" void kernel_launch(void* const* d_in, const int* in_sizes, int n_in,
                              void* d_out, int out_size, void* d_ws, size_t ws_size,
                              hipStream_t stream) {
    const float* gw = (const float*)d_in[0];
    const float* hn = (const float*)d_in[1];
    const float* h0 = (const float*)d_in[2];
    float* out = (float*)d_out;

    constexpr int total = B * H * CPR;       // 856064 threads
    constexpr int block = 256;
    constexpr int grid = total / block;      // 3344 exact
    cspn_r6_kernel<<<grid, block, 0, stream>>>(gw, hn, h0, out);
}

// Round 8
// 28.054 us; speedup vs baseline: 1.4492x; 1.2112x over previous
//
#include <hip/hip_runtime.h>
#include <hip/hip_bf16.h>

// CSPN step: out[b,y,x] = sum_{i,j} gw[b, i*3+j, y+1, x+1] * src[y+1-i, x+1-j]
// src = h0 for center tap (i=j=1), hn otherwise; zero outside [0,H)x[0,W).
// R7 = R6 body (4 px/thread, one dwordx4 per gw tap, all loads issued first)
// + bijective XCD swizzle pinning batch b to XCD b (hn_b+h0_b = 3.4MB < 4MB L2).

constexpr int B = 8;
constexpr int H = 352;
constexpr int W = 1216;
constexpr int HP = H + 2;            // 354
constexpr int WP = W + 2;            // 1218
constexpr int CPR = W / 4;           // 304 chunks per row, exact
constexpr size_t PLANE = (size_t)HP * WP;
constexpr int NBLK = B * H * CPR / 256;   // 3344 = 8 * 418; 418 blocks = 1 batch

typedef float f4  __attribute__((ext_vector_type(4)));               // 16B aligned
typedef float f4u __attribute__((ext_vector_type(4), aligned(4)));   // dword aligned

__global__ __launch_bounds__(256) void cspn_r7_kernel(
    const float* __restrict__ gw,   // [B, 9, HP, WP]
    const float* __restrict__ hn,   // [B, 1, H, W]
    const float* __restrict__ h0,   // [B, 1, H, W]
    float* __restrict__ out)        // [B, 1, H, W]
{
    // XCD swizzle: hw maps dispatch id d -> XCD d%8; remap so XCD k runs
    // logical blocks [418k, 418k+418) == exactly batch k (linear within).
    int bid = blockIdx.x;
    int swz = (bid & 7) * (NBLK / 8) + (bid >> 3);
    int tid = swz * 256 + threadIdx.x;

    int cx = tid % CPR;
    int t2 = tid / CPR;
    int y  = t2 % H;
    int b  = t2 / H;
    int x0 = cx * 4;

    const float* hnb = hn + (size_t)b * H * W;
    const float* h0p = h0 + (size_t)b * H * W + (size_t)y * W + x0;
    const float* gwp = gw + (size_t)b * 9 * PLANE + (size_t)(y + 1) * WP + (x0 + 1);
    float* outp = out + (size_t)b * H * W + (size_t)y * W + x0;

    // ---- issue ALL loads first (14 independent memory ops) ----
    f4u g[9];
#pragma unroll
    for (int t = 0; t < 9; ++t)
        g[t] = *reinterpret_cast<const f4u*>(gwp + (size_t)t * PLANE);

    int aL = (cx > 0)       ? x0 - 1 : 0;
    int aR = (cx < CPR - 1) ? x0 + 4 : W - 1;
    int ay0 = (y < H - 1) ? y + 1 : y;     // clamped row for i=0
    int ay2 = (y > 0)     ? y - 1 : y;     // clamped row for i=2
    const float* rp0 = hnb + (size_t)ay0 * W;
    const float* rp1 = hnb + (size_t)y * W;
    const float* rp2 = hnb + (size_t)ay2 * W;

    f4 v0 = *reinterpret_cast<const f4*>(rp0 + x0);
    float sL0 = rp0[aL], sR0 = rp0[aR];
    f4 v1 = *reinterpret_cast<const f4*>(rp1 + x0);
    float sL1 = rp1[aL], sR1 = rp1[aR];
    f4 v2 = *reinterpret_cast<const f4*>(rp2 + x0);
    float sL2 = rp2[aL], sR2 = rp2[aR];

    f4 c = *reinterpret_cast<const f4*>(h0p);

    // ---- masks / register shuffle (no memory) ----
    bool okL = (cx > 0), okR = (cx < CPR - 1);
    bool ok0 = (y < H - 1), ok2 = (y > 0);
    float m0 = ok0 ? 1.f : 0.f;
    float m2 = ok2 ? 1.f : 0.f;

    float r[3][6];
    r[0][0] = (ok0 & okL) ? sL0 : 0.f;
    r[0][1] = v0[0] * m0; r[0][2] = v0[1] * m0;
    r[0][3] = v0[2] * m0; r[0][4] = v0[3] * m0;
    r[0][5] = (ok0 & okR) ? sR0 : 0.f;

    r[1][0] = okL ? sL1 : 0.f;
    r[1][1] = v1[0]; r[1][2] = v1[1];
    r[1][3] = v1[2]; r[1][4] = v1[3];
    r[1][5] = okR ? sR1 : 0.f;

    r[2][0] = (ok2 & okL) ? sL2 : 0.f;
    r[2][1] = v2[0] * m2; r[2][2] = v2[1] * m2;
    r[2][3] = v2[2] * m2; r[2][4] = v2[3] * m2;
    r[2][5] = (ok2 & okR) ? sR2 : 0.f;

    // ---- FMAs ----
    float acc[4] = {0.f, 0.f, 0.f, 0.f};
#pragma unroll
    for (int i = 0; i < 3; ++i) {
#pragma unroll
        for (int j = 0; j < 3; ++j) {
            const int t = i * 3 + j;
#pragma unroll
            for (int p = 0; p < 4; ++p) {
                float s = (t == 4) ? c[p] : r[i][p + 2 - j];
                acc[p] = fmaf(g[t][p], s, acc[p]);
            }
        }
    }

    f4 o; o[0] = acc[0]; o[1] = acc[1]; o[2] = acc[2]; o[3] = acc[3];
    *reinterpret_cast<f4*>(outp) = o;   // 16B aligned
}

extern "C" void kernel_launch(void* const* d_in, const int* in_sizes, int n_in,
                              void* d_out, int out_size, void* d_ws, size_t ws_size,
                              hipStream_t stream) {
    const float* gw = (const float*)d_in[0];
    const float* hn = (const float*)d_in[1];
    const float* h0 = (const float*)d_in[2];
    float* out = (float*)d_out;

    cspn_r7_kernel<<<NBLK, 256, 0, stream>>>(gw, hn, h0, out);
}